// Round 4
// baseline (146.118 us; speedup 1.0000x reference)
//
#include <hip/hip_runtime.h>
#include <hip/hip_fp16.h>

// B=8, T=S=512, M=N=512, H=128
// score[b,t,s] = (1/sqrt(512)) * sum_h v[h]*tanh(x1[b,t,h]+x2[b,s,h])
// tanh(x) = 1 - 2/(1+e^{2x}) => score = (Sv - 2*sum_h v_h*sigma_h)/SCALE,
//   sigma = 1/(1+e), e = exp2(z1+z2), z_i = 2*log2(e)*x_i.
// Round-4 format: proj stores w = bits(em) with low 10 mantissa bits
// replaced by k (10-bit two's complement), where exp2(z1) = em * 2^k,
// em in [0.707,1.414]. Score reads em = as_float(w) directly (k bits are
// 1.7e-4 relative mantissa noise, below the f16 noise that already passed)
// and k = sbfe(w,0,10). Hot loop per element: mul + iadd + imin + ldexp
// + add1 (5 VALU slots, no transcendental) then 4-way rcp merge:
// v1/a1+..+v4/a4 = num/(a1a2a3a4), one rcp per 4 elements.

constexpr float SCALE_IN  = 2.8853900817779268f;   // 2*log2(e)
constexpr float INV_SCALE = 0.04419417382415922f;  // 1/sqrt(512)

// ---------------- Projection GEMM + stuffed exp-factor pack ------------------
// Fused full-K (round-0 structure, session-verified): grid 256 blocks
// (128 per matrix), 512 threads. Block: 32 rows x 128 h. LDS: A 32x64 (8KB)
// + W 64x128 (32KB). Thread: 2 rows x 4 h.
__global__ __launch_bounds__(512) void proj_kernel(
    const float* __restrict__ q,  const float* __restrict__ w2,
    const float* __restrict__ ky, const float* __restrict__ w1,
    unsigned int* __restrict__ x1w, unsigned int* __restrict__ x2w) {
  __shared__ float As[32 * 64];    // [row][k]
  __shared__ float Ws[64 * 128];   // [k][h]

  int blk = blockIdx.x;
  const float* A; const float* W; unsigned int* O;
  if (blk < 128) { A = q;  W = w2; O = x1w; }
  else           { blk -= 128; A = ky; W = w1; O = x2w; }
  const int rbase = blk * 32;
  const int tid = threadIdx.x;

  const int rq = tid >> 5;          // 0..15 -> rows 2*rq+{0,1}
  const int hq = tid & 31;          // h = 4*hq+{0..3}

  float acc[2][4];
#pragma unroll
  for (int r = 0; r < 2; ++r)
#pragma unroll
    for (int c = 0; c < 4; ++c) acc[r][c] = 0.0f;

  for (int kb = 0; kb < 512; kb += 64) {
    // stage A: 2048 floats, 1 float4/thread (coalesced 16-lane rows)
    {
      const int arow = tid >> 4;          // 0..31
      const int kq4  = (tid & 15) * 4;
      *(float4*)(As + arow * 64 + kq4) =
          *(const float4*)(A + (size_t)(rbase + arow) * 512 + kb + kq4);
      // stage W: 8192 floats, 4 float4/thread (coalesced 32-lane rows)
      const int wrow = tid >> 5;          // 0..15
      const int hq4  = (tid & 31) * 4;
#pragma unroll
      for (int p = 0; p < 4; ++p)
        *(float4*)(Ws + (wrow + 16 * p) * 128 + hq4) =
            *(const float4*)(W + (size_t)(kb + wrow + 16 * p) * 128 + hq4);
    }
    __syncthreads();
#pragma unroll 4
    for (int k4 = 0; k4 < 64; k4 += 4) {
      float a[2][4], w[4][4];
      *(float4*)a[0] = *(const float4*)(As + (2 * rq + 0) * 64 + k4);
      *(float4*)a[1] = *(const float4*)(As + (2 * rq + 1) * 64 + k4);
#pragma unroll
      for (int kk = 0; kk < 4; ++kk)
        *(float4*)w[kk] = *(const float4*)(Ws + (k4 + kk) * 128 + 4 * hq);
#pragma unroll
      for (int kk = 0; kk < 4; ++kk)
#pragma unroll
        for (int r = 0; r < 2; ++r)
#pragma unroll
          for (int c = 0; c < 4; ++c)
            acc[r][c] = fmaf(a[r][kk], w[kk][c], acc[r][c]);
    }
    __syncthreads();
  }

  // epilogue: z = acc*2log2e ; exp2(z) = em*2^k ;
  // pack w = (bits(em) & ~1023) | (k & 1023), k clamped to [-512,511]
  // (|z| <= ~460 for 6-sigma inputs, clamp is a safety net in saturation).
#pragma unroll
  for (int r = 0; r < 2; ++r) {
    unsigned int pk[4];
#pragma unroll
    for (int c = 0; c < 4; ++c) {
      const float z  = acc[r][c] * SCALE_IN;
      const float kf = rintf(z);
      int ki = (int)kf;
      ki = max(min(ki, 511), -512);
      const float em = __builtin_amdgcn_exp2f(z - kf);   // in [0.707,1.414]
      pk[c] = (__float_as_uint(em) & 0xFFFFFC00u) | ((unsigned int)ki & 1023u);
    }
    *(uint4*)(O + (size_t)(rbase + 2 * rq + r) * 128 + 4 * hq) = *(uint4*)pk;
  }
}

// ---------------- Main score kernel -----------------------------------------
// 512 blocks x 512 threads. Tile 64(t) x 64(s), H in two 64-h phases.
// LDS 32KB ([64h][64t] + [64h][64s] u32). Thread: 2 t x 4 s.
// Per element: e = ldexp(emt*ems, min(kt+ks,30)); a = e+1; 4-way rcp merge.
__global__ __launch_bounds__(512, 4) void score_kernel(
    const unsigned int* __restrict__ x1w, const unsigned int* __restrict__ x2w,
    const float* __restrict__ v, float* __restrict__ out) {
  __shared__ unsigned int x1l[64 * 64];  // [h(64)][t(64)] 16KB
  __shared__ unsigned int x2l[64 * 64];  // [h(64)][s(64)] 16KB

  const int tid   = threadIdx.x;
  const int b     = blockIdx.x >> 6;
  const int tile  = blockIdx.x & 63;
  const int tbase = (tile >> 3) * 64;    // 8 t-tiles
  const int sbase = (tile & 7) * 64;     // 8 s-tiles

  const unsigned int* x1g = x1w + (size_t)(b * 512 + tbase) * 128;
  const unsigned int* x2g = x2w + (size_t)(b * 512 + sbase) * 128;

  const int sg = tid & 15;   // s = 4*sg+j (coalesced float4 stores)
  const int tg = tid >> 4;   // 0..31, t = 2*tg+i

  float racc[2][4];
#pragma unroll
  for (int i = 0; i < 2; ++i)
#pragma unroll
    for (int j = 0; j < 4; ++j) racc[i][j] = 0.0f;
  float sv = 0.0f;

  for (int ph = 0; ph < 2; ++ph) {
    // transposed staging: [row][h] global -> [h][row] LDS.
    // writes: 64 lanes hit 256B contiguous -> 2-way banks (free)
    {
      const int r1 = tid & 63;            // row within tile
      const int c0 = tid >> 6;            // 0..7
#pragma unroll
      for (int p = 0; p < 2; ++p) {
        const int c = c0 + 8 * p;         // 0..15 -> h = 4c..4c+3
        const uint4 a =
            *(const uint4*)(x1g + (size_t)r1 * 128 + ph * 64 + 4 * c);
        x1l[(4 * c + 0) * 64 + r1] = a.x;
        x1l[(4 * c + 1) * 64 + r1] = a.y;
        x1l[(4 * c + 2) * 64 + r1] = a.z;
        x1l[(4 * c + 3) * 64 + r1] = a.w;
        const uint4 s =
            *(const uint4*)(x2g + (size_t)r1 * 128 + ph * 64 + 4 * c);
        x2l[(4 * c + 0) * 64 + r1] = s.x;
        x2l[(4 * c + 1) * 64 + r1] = s.y;
        x2l[(4 * c + 2) * 64 + r1] = s.z;
        x2l[(4 * c + 3) * 64 + r1] = s.w;
      }
    }
    __syncthreads();

    for (int hg = 0; hg < 16; ++hg) {
      const int h0 = hg * 4;
      const float4 vq = *(const float4*)(v + ph * 64 + h0);  // uniform s_load
      sv += (vq.x + vq.y) + (vq.z + vq.w);

      float emt[2][4]; int kt[2][4];
      float ems[4][4]; int ks[4][4];
#pragma unroll
      for (int qq = 0; qq < 4; ++qq) {
        const uint2 tp = *(const uint2*)(x1l + (h0 + qq) * 64 + 2 * tg);
        emt[0][qq] = __uint_as_float(tp.x);              // k bits = noise
        kt [0][qq] = (int)(tp.x << 22) >> 22;            // v_bfe_i32
        emt[1][qq] = __uint_as_float(tp.y);
        kt [1][qq] = (int)(tp.y << 22) >> 22;
        const uint4 sp = *(const uint4*)(x2l + (h0 + qq) * 64 + 4 * sg);
        ems[0][qq] = __uint_as_float(sp.x);
        ks [0][qq] = (int)(sp.x << 22) >> 22;
        ems[1][qq] = __uint_as_float(sp.y);
        ks [1][qq] = (int)(sp.y << 22) >> 22;
        ems[2][qq] = __uint_as_float(sp.z);
        ks [2][qq] = (int)(sp.z << 22) >> 22;
        ems[3][qq] = __uint_as_float(sp.w);
        ks [3][qq] = (int)(sp.w << 22) >> 22;
      }

#pragma unroll
      for (int i = 0; i < 2; ++i) {
#pragma unroll
        for (int j = 0; j < 4; ++j) {
          float e[4];
#pragma unroll
          for (int qq = 0; qq < 4; ++qq) {
            int kk = kt[i][qq] + ks[j][qq];
            kk = min(kk, 30);                     // den <= 2^124, no inf/NaN
            e[qq] = ldexpf(emt[i][qq] * ems[j][qq], kk);
          }
          const float a0 = e[0] + 1.0f, a1 = e[1] + 1.0f;
          const float a2 = e[2] + 1.0f, a3 = e[3] + 1.0f;
          const float p12 = a0 * a1, p34 = a2 * a3;
          float u1 = vq.x * a1; u1 = fmaf(vq.y, a0, u1);
          float u2 = vq.z * a3; u2 = fmaf(vq.w, a2, u2);
          float num = u1 * p34; num = fmaf(u2, p12, num);
          const float den = p12 * p34;
          racc[i][j] = fmaf(num, __builtin_amdgcn_rcpf(den), racc[i][j]);
        }
      }
    }
    __syncthreads();   // before next phase overwrites LDS
  }

  const float c1v = sv * INV_SCALE;
  const float c2v = -2.0f * INV_SCALE;
#pragma unroll
  for (int i = 0; i < 2; ++i) {
    const int t = tbase + 2 * tg + i;
    float4 o;
    o.x = fmaf(racc[i][0], c2v, c1v);
    o.y = fmaf(racc[i][1], c2v, c1v);
    o.z = fmaf(racc[i][2], c2v, c1v);
    o.w = fmaf(racc[i][3], c2v, c1v);
    *(float4*)(out + (size_t)(b * 512 + t) * 512 + sbase + 4 * sg) = o;
  }
}

extern "C" void kernel_launch(void* const* d_in, const int* in_sizes, int n_in,
                              void* d_out, int out_size, void* d_ws, size_t ws_size,
                              hipStream_t stream) {
  const float* query = (const float*)d_in[0];  // (8,512,512)
  const float* keys  = (const float*)d_in[1];  // (8,512,512)
  const float* W1    = (const float*)d_in[2];  // (512,128) pairs with keys
  const float* W2    = (const float*)d_in[3];  // (512,128) pairs with query
  const float* v     = (const float*)d_in[4];  // (128,)
  float* out = (float*)d_out;                  // (8,512,512) fp32

  unsigned int* x1w = (unsigned int*)d_ws;     // 8*512*128 stuffed f32 (2 MB)
  unsigned int* x2w = x1w + 8 * 512 * 128;     // 2 MB more

  hipLaunchKernelGGL(proj_kernel, dim3(256), dim3(512), 0, stream,
                     query, W2, keys, W1, x1w, x2w);
  hipLaunchKernelGGL(score_kernel, dim3(512), dim3(512), 0, stream,
                     x1w, x2w, v, out);
}